// Round 1
// baseline (1503.707 us; speedup 1.0000x reference)
//
#include <hip/hip_runtime.h>

// LSTMModel: 4-layer LSTM (H=50, IN=7, B=1024, T=512) + FC(50->25 relu ->1).
// Fused persistent kernel: 256 blocks x 1024 threads, 4 batch elems per block.
// Layer-pipelined over time: at tick s, layer l processes t = s - l.
// Weights in VGPRs as packed fp16; dot products via v_dot2_f32_f16 (fp32 acc).
// Cell state c, gate preacts, FC head in fp32. h in LDS as fp16.

#define H 50
#define G4 200          // 4*H gates
#define INSZ 7
#define BATCH 1024
#define TT 512
#define NL 4
#define FC1N 25
#define BPG 4           // batch elements per block
#define NBLK (BATCH / BPG)
#define HP 56           // padded h length in halves (16B-aligned rows)
#define NTHREADS 1024

typedef _Float16 half_t;
typedef __attribute__((ext_vector_type(2))) _Float16 half2_t;

struct Params {
  const float* x;
  const float* Wih[NL];
  const float* Whh[NL];
  const float* bih[NL];
  const float* bhh[NL];
  const float* W1;
  const float* b1;
  const float* W2;
  const float* b2;
  float* out;
};

__device__ __forceinline__ float dot2(half2_t a, half2_t b, float c) {
#if __has_builtin(__builtin_amdgcn_fdot2)
  return __builtin_amdgcn_fdot2(a, b, c, false);
#else
  return c + (float)a[0] * (float)b[0] + (float)a[1] * (float)b[1];
#endif
}

__device__ __forceinline__ float sigf(float x) { return 1.0f / (1.0f + __expf(-x)); }
// tanh via sigmoid: overflow-safe (exp->inf gives 0 or 1, never NaN)
__device__ __forceinline__ float tanh_fast(float x) { return 2.0f * sigf(2.0f * x) - 1.0f; }

__global__ __launch_bounds__(NTHREADS) void lstm_fused(Params p) {
  __shared__ __align__(16) half_t h_buf[NL][2][BPG][HP];  // [layer][t&1][b][unit]
  __shared__ __align__(16) half_t x_buf[2][BPG][8];       // x prefetch double-buffer
  __shared__ float gates[NL][BPG][G4];
  __shared__ float c_lds[NL][BPG][H];
  __shared__ float fc_h[BPG][H];
  __shared__ float fc1_buf[BPG][FC1N];

  const int tid = threadIdx.x;
  const int b0 = blockIdx.x * BPG;

  // --- gate role: layer group = tid>>8, gate index = tid&255 (active < 200)
  const int lay = tid >> 8;
  const int gg = tid & 255;
  const bool is_gate = (gg < G4);

  // --- cell-update role: tid < 800 covers (layer, b, unit) one each
  const bool is_upd = (tid < NL * BPG * H);
  const int ulay = tid / (BPG * H);
  const int urem = tid % (BPG * H);
  const int ub = urem / H;
  const int uj = urem % H;

  // --- x prefetch role: tids [800, 828)
  const int lt = tid - 800;
  const bool is_load = (lt >= 0) && (lt < BPG * INSZ);
  const int lb = (lt >= 0) ? lt / INSZ : 0;
  const int lk = (lt >= 0) ? lt % INSZ : 0;

  // --- load this thread's weight rows into registers as fp16 pairs
  half2_t wih2[25], whh2[25];
  float bias_g = 0.0f;
  if (is_gate) {
    const int isz = (lay == 0) ? INSZ : H;
    const float* wr = p.Wih[lay] + (size_t)gg * isz;
#pragma unroll
    for (int k = 0; k < 25; ++k) {
      float a = (2 * k < isz) ? wr[2 * k] : 0.0f;
      float b = (2 * k + 1 < isz) ? wr[2 * k + 1] : 0.0f;
      half2_t v = {(half_t)a, (half_t)b};
      wih2[k] = v;
    }
    const float* hr = p.Whh[lay] + (size_t)gg * H;
#pragma unroll
    for (int k = 0; k < 25; ++k) {
      half2_t v = {(half_t)hr[2 * k], (half_t)hr[2 * k + 1]};
      whh2[k] = v;
    }
    bias_g = p.bih[lay][gg] + p.bhh[lay][gg];
  }

  // --- zero LDS state
  for (int i = tid; i < NL * 2 * BPG * HP; i += NTHREADS) ((half_t*)h_buf)[i] = (half_t)0.0f;
  for (int i = tid; i < 2 * BPG * 8; i += NTHREADS) ((half_t*)x_buf)[i] = (half_t)0.0f;
  for (int i = tid; i < NL * BPG * H; i += NTHREADS) ((float*)c_lds)[i] = 0.0f;
  __syncthreads();
  // preload x at t=0 (after the zero pass is globally done)
  if (tid < BPG * INSZ) {
    int b = tid / INSZ, k = tid % INSZ;
    x_buf[0][b][k] = (half_t)p.x[((size_t)(b0 + b) * TT + 0) * INSZ + k];
  }
  __syncthreads();

  // --- main pipelined time loop: ticks s = 0 .. T+NL-2
  for (int s = 0; s < TT + NL - 1; ++s) {
    // prefetch next x (consumed by layer 0 at tick s+1)
    float xreg = 0.0f;
    const int tn = s + 1;
    if (is_load && tn < TT)
      xreg = p.x[((size_t)(b0 + lb) * TT + tn) * INSZ + lk];

    // phase A: gate pre-activations
    const int tg = s - lay;
    if (is_gate && tg >= 0 && tg < TT) {
      const int par = tg & 1;
#pragma unroll
      for (int b = 0; b < BPG; ++b) {
        float acc = bias_g;
        if (lay == 0) {
          const half2_t* xv = (const half2_t*)&x_buf[par][b][0];
#pragma unroll
          for (int k = 0; k < 4; ++k) acc = dot2(wih2[k], xv[k], acc);
        } else {
          const half2_t* iv = (const half2_t*)&h_buf[lay - 1][par][b][0];
#pragma unroll
          for (int k = 0; k < 25; ++k) acc = dot2(wih2[k], iv[k], acc);
        }
        const half2_t* hv = (const half2_t*)&h_buf[lay][par ^ 1][b][0];
#pragma unroll
        for (int k = 0; k < 25; ++k) acc = dot2(whh2[k], hv[k], acc);
        gates[lay][b][gg] = acc;
      }
    }
    __syncthreads();

    // phase C: cell update (one (layer,b,unit) per thread, spread across waves)
    const int tu = s - ulay;
    if (is_upd && tu >= 0 && tu < TT) {
      float gi = sigf(gates[ulay][ub][uj]);
      float gf = sigf(gates[ulay][ub][H + uj]);
      float gc = tanh_fast(gates[ulay][ub][2 * H + uj]);
      float go = sigf(gates[ulay][ub][3 * H + uj]);
      float c = gf * c_lds[ulay][ub][uj] + gi * gc;
      c_lds[ulay][ub][uj] = c;
      float h = go * tanh_fast(c);
      h_buf[ulay][tu & 1][ub][uj] = (half_t)h;
      if (ulay == NL - 1 && tu == TT - 1) fc_h[ub][uj] = h;  // keep fp32 for FC
    }
    // commit prefetched x into the other parity slot
    if (is_load && tn < TT) x_buf[tn & 1][lb][lk] = (half_t)xreg;
    __syncthreads();
  }

  // --- FC head (fp32): h_last @ W1^T + b1, relu, @ W2^T + b2
  if (tid < BPG * FC1N) {
    const int b = tid / FC1N, j = tid % FC1N;
    const float* w = p.W1 + j * H;
    float a = p.b1[j];
#pragma unroll
    for (int k = 0; k < H; ++k) a += fc_h[b][k] * w[k];
    fc1_buf[b][j] = fmaxf(a, 0.0f);
  }
  __syncthreads();
  if (tid < BPG) {
    float a = p.b2[0];
#pragma unroll
    for (int j = 0; j < FC1N; ++j) a += fc1_buf[tid][j] * p.W2[j];
    p.out[b0 + tid] = a;
  }
}

extern "C" void kernel_launch(void* const* d_in, const int* in_sizes, int n_in,
                              void* d_out, int out_size, void* d_ws, size_t ws_size,
                              hipStream_t stream) {
  Params p;
  p.x = (const float*)d_in[0];
  for (int l = 0; l < NL; ++l) {
    p.Wih[l] = (const float*)d_in[1 + 4 * l];
    p.Whh[l] = (const float*)d_in[2 + 4 * l];
    p.bih[l] = (const float*)d_in[3 + 4 * l];
    p.bhh[l] = (const float*)d_in[4 + 4 * l];
  }
  p.W1 = (const float*)d_in[17];
  p.b1 = (const float*)d_in[18];
  p.W2 = (const float*)d_in[19];
  p.b2 = (const float*)d_in[20];
  p.out = (float*)d_out;

  hipLaunchKernelGGL(lstm_fused, dim3(NBLK), dim3(NTHREADS), 0, stream, p);
}